// Round 1
// baseline (269.355 us; speedup 1.0000x reference)
//
#include <hip/hip_runtime.h>
#include <hip/hip_bf16.h>

#define N_PTS   131072
#define N_FEATS 1000
#define FDIM    64
#define HID     128
#define NCHUNK  32          // 32 K-chunks of 32 features (padded 1000 -> 1024)
#define PI_F    3.14159265358979f
#define L2E     1.44269504f

typedef short  short8  __attribute__((ext_vector_type(8)));   // bf16 A/B frag (4 VGPRs)
typedef float  floatx4 __attribute__((ext_vector_type(4)));   // C/D frag
typedef float  f4      __attribute__((ext_vector_type(4)));

// ---- bf16 helpers ----
__device__ __forceinline__ unsigned int packbf2(float a, float b) {
    float2 t; t.x = a; t.y = b;
    __hip_bfloat162 h = __float22bfloat162_rn(t);
    union { __hip_bfloat162 hh; unsigned int u; } cv; cv.hh = h;
    return cv.u;
}
__device__ __forceinline__ unsigned short f2bf(float f) {      // RNE, 1 v_cvt_pk
    return (unsigned short)packbf2(f, f);
}
__device__ __forceinline__ float bf2f(unsigned short h) {
    return __uint_as_float(((unsigned int)h) << 16);
}
__device__ __forceinline__ f4 min4(f4 a, f4 b) {
    f4 r;
    r[0] = fminf(a[0], b[0]); r[1] = fminf(a[1], b[1]);
    r[2] = fminf(a[2], b[2]); r[3] = fminf(a[3], b[3]);
    return r;
}
// shifted squared distance: t = |loc|^2 - 2 x.loc  (d2 = t + |x|^2)
// MUST be used identically in pass 1 and pass 2 so rounding matches exactly.
__device__ __forceinline__ f4 shifted_d2(f4 lx, f4 ly, f4 lz, f4 sl,
                                         float x0, float x1, float x2) {
    f4 d = lx*x0; d += ly*x1; d += lz*x2;       // mul + fma + fma
    return sl - 2.f*d;                          // fma(d, -2, sl)
}

// ---------------- fused prep: SoA locs (+|loc|^2) + bf16 fragment-ordered fv / W ----
// i in [0,65536): fvB   [cq=chunk*4+quad][n=0..63][j=0..7]
// i in [65536,131072): WB (4 layers)  [cq][n=0..127][j=0..7], layer0 K padded 100->128
// i in [131072,132096): LX/LY/LZ/SL [1024], pads at 1e9 (never the min distance)
__global__ void prep_all(const float* __restrict__ locs, const float* __restrict__ fv,
                         const float* __restrict__ W0, const float* __restrict__ W1,
                         const float* __restrict__ W2, const float* __restrict__ W3,
                         float* __restrict__ LX, float* __restrict__ LY, float* __restrict__ LZ,
                         float* __restrict__ SL,
                         unsigned short* __restrict__ fvB, unsigned short* __restrict__ WB)
{
    int i = blockIdx.x * 256 + threadIdx.x;
    if (i < 65536) {
        int j = i & 7, n = (i >> 3) & 63, cq = i >> 9;
        int f = (cq >> 2) * 32 + (cq & 3) * 8 + j;
        float v = (f < N_FEATS) ? fv[f*FDIM + n] : 0.f;
        fvB[i] = f2bf(v);
    } else if (i < 131072) {
        int r = i - 65536;
        int L = r >> 14, rr = r & 16383;
        int j = rr & 7, n = (rr >> 3) & 127, cq = rr >> 10;
        int k = (cq >> 2) * 32 + (cq & 3) * 8 + j;
        const float* W = (L == 0) ? W0 : (L == 1) ? W1 : (L == 2) ? W2 : W3;
        int Kin = (L == 0) ? 100 : 128;
        float v = (k < Kin) ? W[n*Kin + k] : 0.f;
        WB[r] = f2bf(v);
    } else if (i < 132096) {
        int t = i - 131072;
        bool val = t < N_FEATS;
        float lx = val ? locs[t*3+0] : 1e9f;
        float ly = val ? locs[t*3+1] : 1e9f;
        float lz = val ? locs[t*3+2] : 1e9f;
        LX[t] = lx; LY[t] = ly; LZ[t] = lz;
        SL[t] = lx*lx + ly*ly + lz*lz;          // 3e18 for pads -> never min
    }
}

// ---------------- main fused kernel ----------------
// 4 waves/block, 16 points/wave, no __syncthreads (act rows are wave-private).
// launch_bounds(256,6): 6 blocks/CU = 24 waves/CU; VGPR cap 85 >> current use.
__global__ __launch_bounds__(256, 6)
void afvsrn_mfma(const float* __restrict__ x,
                 const float* __restrict__ LX, const float* __restrict__ LY,
                 const float* __restrict__ LZ, const float* __restrict__ SL,
                 const unsigned short* __restrict__ fvB,
                 const unsigned short* __restrict__ WB,
                 const float* __restrict__ b0, const float* __restrict__ b1,
                 const float* __restrict__ b2, const float* __restrict__ b3,
                 const float* __restrict__ W4, const float* __restrict__ b4,
                 float* __restrict__ out)
{
    __shared__ unsigned short act[64 * 136];   // [64 pts][128 + 8 pad] bf16

    const int lane = threadIdx.x & 63;
    const int wv   = threadIdx.x >> 6;
    const int ptl  = lane & 15;                // A-frag row m / C-frag col n
    const int quad = lane >> 4;                // A/B-frag k-group, C-frag row-group
    const int ptbase = blockIdx.x * 64 + wv * 16;

    const float x0 = x[(ptbase + ptl)*3 + 0];
    const float x1 = x[(ptbase + ptl)*3 + 1];
    const float x2 = x[(ptbase + ptl)*3 + 2];
    const float A  = x0*x0 + x1*x1 + x2*x2;

    const f4* LX4 = (const f4*)LX;
    const f4* LY4 = (const f4*)LY;
    const f4* LZ4 = (const f4*)LZ;
    const f4* SL4 = (const f4*)SL;

    // ---------- pass 1: min shifted-d2 only (no transcendentals) ----------
    f4 mn = {1e30f, 1e30f, 1e30f, 1e30f};
    #pragma unroll 2
    for (int c = 0; c < NCHUNK; ++c) {
        int g = c*8 + quad*2;
        f4 t0 = shifted_d2(LX4[g],   LY4[g],   LZ4[g],   SL4[g],   x0, x1, x2);
        f4 t1 = shifted_d2(LX4[g+1], LY4[g+1], LZ4[g+1], SL4[g+1], x0, x1, x2);
        mn = min4(mn, t0);
        mn = min4(mn, t1);
    }
    float md = fminf(fminf(mn[0], mn[1]), fminf(mn[2], mn[3]));
    md = fminf(md, __shfl_xor(md, 16));
    md = fminf(md, __shfl_xor(md, 32));
    // m = max inv_d = rsqrt(min d2). RN add is monotonic, so min over t + A
    // equals min over (t+A): pass-2 arg of rsq is bit-identical for the argmin.
    const float m   = __builtin_amdgcn_rsqf(fmaxf(md + A, 1e-12f));
    const float nmB = -m * L2E;

    // ---------- pass 2: p = exp2(fma(inv_d, log2e, -m*log2e)); GEMM feats = w @ fv ----------
    // ls comes free from an extra MFMA against an all-ones B tile: its C-frag
    // row (quad*4+r) is exactly the point whose linv each lane needs -> no shuffles.
    const short8 ONES = {0x3F80,0x3F80,0x3F80,0x3F80,0x3F80,0x3F80,0x3F80,0x3F80};
    floatx4 acc2[4] = {};
    floatx4 accL = {};
    #pragma unroll 2
    for (int c = 0; c < NCHUNK; ++c) {
        int g = c*8 + quad*2;
        f4 t0 = shifted_d2(LX4[g],   LY4[g],   LZ4[g],   SL4[g],   x0, x1, x2);
        f4 t1 = shifted_d2(LX4[g+1], LY4[g+1], LZ4[g+1], SL4[g+1], x0, x1, x2);
        // last chunk: features 992..1023, only quad 0 (992..999) is real.
        // nm = -inf makes exp2 return exactly 0 for the pad lanes.
        const float nm = ((c == NCHUNK-1) && (quad != 0)) ? -__builtin_inff() : nmB;
        f4 p0, p1;
        #pragma unroll
        for (int e = 0; e < 4; ++e) {
            float iv0 = __builtin_amdgcn_rsqf(fmaxf(t0[e] + A, 1e-12f));
            float iv1 = __builtin_amdgcn_rsqf(fmaxf(t1[e] + A, 1e-12f));
            // clamp at 16: harmless normally (arg <= ~0), bounds p if rounding
            // between passes ever mismatches (2^16 is bf16-safe).
            p0[e] = __builtin_amdgcn_exp2f(fminf(fmaf(iv0, L2E, nm), 16.f));
            p1[e] = __builtin_amdgcn_exp2f(fminf(fmaf(iv1, L2E, nm), 16.f));
        }
        union { short8 v; unsigned int u[4]; } af;
        af.u[0] = packbf2(p0[0], p0[1]);
        af.u[1] = packbf2(p0[2], p0[3]);
        af.u[2] = packbf2(p1[0], p1[1]);
        af.u[3] = packbf2(p1[2], p1[3]);
        const short8* bp = (const short8*)fvB + (c*4 + quad)*64;
        #pragma unroll
        for (int nt = 0; nt < 4; ++nt) {
            short8 b = bp[nt*16 + ptl];
            acc2[nt] = __builtin_amdgcn_mfma_f32_16x16x32_bf16(af.v, b, acc2[nt], 0, 0, 0);
        }
        accL = __builtin_amdgcn_mfma_f32_16x16x32_bf16(af.v, ONES, accL, 0, 0, 0);
    }
    float linv_r[4];
    #pragma unroll
    for (int r = 0; r < 4; ++r) linv_r[r] = __builtin_amdgcn_rcpf(accL[r]);

    // ---------- stage y = [PE(36) | feats(64) | zero pad to 128] ----------
    const int myrow = (wv*16 + ptl) * 136;
    *(short8*)&act[myrow + 96 + quad*8] = (short8)0;

    #pragma unroll
    for (int i = 0; i < 9; ++i) {
        int k = quad*9 + i;
        int d = k / 12, r12 = k % 12, l = r12 % 6;
        float xv = (d == 0) ? x0 : (d == 1) ? x1 : x2;
        float ang = xv * (PI_F * (float)(1 << l));
        float v = (r12 < 6) ? __sinf(ang) : __cosf(ang);
        act[myrow + k] = f2bf(v);
    }

    #pragma unroll
    for (int nt = 0; nt < 4; ++nt)
        #pragma unroll
        for (int r = 0; r < 4; ++r)
            act[(wv*16 + quad*4 + r)*136 + 36 + nt*16 + ptl] = f2bf(acc2[nt][r] * linv_r[r]);

    // ---------- MLP layers 0..3 via MFMA ----------
    for (int Lyr = 0; Lyr < 4; ++Lyr) {
        const short8* WBp = (const short8*)(WB + Lyr*16384);
        const float* bL = (Lyr == 0) ? b0 : (Lyr == 1) ? b1 : (Lyr == 2) ? b2 : b3;

        short8 a[4];
        #pragma unroll
        for (int c = 0; c < 4; ++c)
            a[c] = *(const short8*)&act[myrow + c*32 + quad*8];

        floatx4 acc[8] = {};
        #pragma unroll
        for (int nt = 0; nt < 8; ++nt) {
            #pragma unroll
            for (int c = 0; c < 4; ++c) {
                short8 b = WBp[(c*4 + quad)*128 + nt*16 + ptl];
                acc[nt] = __builtin_amdgcn_mfma_f32_16x16x32_bf16(a[c], b, acc[nt], 0, 0, 0);
            }
        }
        #pragma unroll
        for (int nt = 0; nt < 8; ++nt) {
            float bias = bL[nt*16 + ptl];
            #pragma unroll
            for (int r = 0; r < 4; ++r) {
                float h = acc[nt][r] + bias;
                float s = __sinf(h);
                h = 0.5f*h + s*s;                       // SnakeAlt
                act[(wv*16 + quad*4 + r)*136 + nt*16 + ptl] = f2bf(h);
            }
        }
    }

    // ---------- layer 4: 128 -> 1 ----------
    float o = 0.f;
    #pragma unroll
    for (int s = 0; s < 4; ++s) {
        short8 av = *(const short8*)&act[myrow + quad*32 + s*8];
        const floatx4* wp = (const floatx4*)W4 + (quad*32 + s*8)/4;
        floatx4 w0 = wp[0], w1 = wp[1];
        o = fmaf(bf2f((unsigned short)av[0]), w0[0], o);
        o = fmaf(bf2f((unsigned short)av[1]), w0[1], o);
        o = fmaf(bf2f((unsigned short)av[2]), w0[2], o);
        o = fmaf(bf2f((unsigned short)av[3]), w0[3], o);
        o = fmaf(bf2f((unsigned short)av[4]), w1[0], o);
        o = fmaf(bf2f((unsigned short)av[5]), w1[1], o);
        o = fmaf(bf2f((unsigned short)av[6]), w1[2], o);
        o = fmaf(bf2f((unsigned short)av[7]), w1[3], o);
    }
    o += __shfl_xor(o, 16);
    o += __shfl_xor(o, 32);
    if (quad == 0) out[ptbase + ptl] = o + b4[0];
}

extern "C" void kernel_launch(void* const* d_in, const int* in_sizes, int n_in,
                              void* d_out, int out_size, void* d_ws, size_t ws_size,
                              hipStream_t stream)
{
    const float* x  = (const float*)d_in[0];
    const float* lc = (const float*)d_in[1];
    const float* fv = (const float*)d_in[2];
    const float* W0 = (const float*)d_in[3];
    const float* b0 = (const float*)d_in[4];
    const float* W1 = (const float*)d_in[5];
    const float* b1 = (const float*)d_in[6];
    const float* W2 = (const float*)d_in[7];
    const float* b2 = (const float*)d_in[8];
    const float* W3 = (const float*)d_in[9];
    const float* b3 = (const float*)d_in[10];
    const float* W4 = (const float*)d_in[11];
    const float* b4 = (const float*)d_in[12];

    char* ws = (char*)d_ws;
    float*          LXp = (float*)(ws + 0);
    float*          LYp = (float*)(ws + 4096);
    float*          LZp = (float*)(ws + 8192);
    float*          SLp = (float*)(ws + 12288);
    unsigned short* fvB = (unsigned short*)(ws + 16384);            // 128 KB
    unsigned short* WB  = (unsigned short*)(ws + 16384 + 131072);   // 128 KB

    prep_all<<<dim3(516), dim3(256), 0, stream>>>(lc, fv, W0, W1, W2, W3,
                                                  LXp, LYp, LZp, SLp, fvB, WB);

    afvsrn_mfma<<<dim3(N_PTS/64), dim3(256), 0, stream>>>(
        x, LXp, LYp, LZp, SLp, fvB, WB, b0, b1, b2, b3, W4, b4, (float*)d_out);
}

// Round 2
// 264.720 us; speedup vs baseline: 1.0175x; 1.0175x over previous
//
#include <hip/hip_runtime.h>
#include <hip/hip_bf16.h>

#define N_PTS   131072
#define N_FEATS 1000
#define FDIM    64
#define HID     128
#define NCHUNK  32          // 32 K-chunks of 32 features (padded 1000 -> 1024)
#define PI_F    3.14159265358979f
#define L2E     1.44269504f

typedef short  short8  __attribute__((ext_vector_type(8)));   // bf16 A/B frag (4 VGPRs)
typedef float  floatx4 __attribute__((ext_vector_type(4)));   // C/D frag
typedef float  f4      __attribute__((ext_vector_type(4)));

// ---- bf16 helpers ----
__device__ __forceinline__ unsigned int packbf2(float a, float b) {
    float2 t; t.x = a; t.y = b;
    __hip_bfloat162 h = __float22bfloat162_rn(t);
    union { __hip_bfloat162 hh; unsigned int u; } cv; cv.hh = h;
    return cv.u;
}
__device__ __forceinline__ unsigned short f2bf(float f) {      // RNE, 1 v_cvt_pk
    return (unsigned short)packbf2(f, f);
}
__device__ __forceinline__ float bf2f(unsigned short h) {
    return __uint_as_float(((unsigned int)h) << 16);
}
__device__ __forceinline__ f4 min4(f4 a, f4 b) {
    f4 r;
    r[0] = fminf(a[0], b[0]); r[1] = fminf(a[1], b[1]);
    r[2] = fminf(a[2], b[2]); r[3] = fminf(a[3], b[3]);
    return r;
}
// shifted squared distance: t = |loc|^2 - 2 x.loc  (d2 = t + |x|^2)
// MUST be used identically in pass 1 and pass 2 so rounding matches exactly.
__device__ __forceinline__ f4 shifted_d2(f4 lx, f4 ly, f4 lz, f4 sl,
                                         float x0, float x1, float x2) {
    f4 d = lx*x0; d += ly*x1; d += lz*x2;       // mul + fma + fma
    return sl - 2.f*d;                          // fma(d, -2, sl)
}

// ---------------- fused prep: SoA locs (+|loc|^2) + bf16 fragment-ordered fv / W ----
// i in [0,65536): fvB   [cq=chunk*4+quad][n=0..63][j=0..7]
// i in [65536,131072): WB (4 layers)  [cq][n=0..127][j=0..7], layer0 K padded 100->128
// i in [131072,132096): LX/LY/LZ/SL [1024], pads at 1e9 (never the min distance)
__global__ void prep_all(const float* __restrict__ locs, const float* __restrict__ fv,
                         const float* __restrict__ W0, const float* __restrict__ W1,
                         const float* __restrict__ W2, const float* __restrict__ W3,
                         float* __restrict__ LX, float* __restrict__ LY, float* __restrict__ LZ,
                         float* __restrict__ SL,
                         unsigned short* __restrict__ fvB, unsigned short* __restrict__ WB)
{
    int i = blockIdx.x * 256 + threadIdx.x;
    if (i < 65536) {
        int j = i & 7, n = (i >> 3) & 63, cq = i >> 9;
        int f = (cq >> 2) * 32 + (cq & 3) * 8 + j;
        float v = (f < N_FEATS) ? fv[f*FDIM + n] : 0.f;
        fvB[i] = f2bf(v);
    } else if (i < 131072) {
        int r = i - 65536;
        int L = r >> 14, rr = r & 16383;
        int j = rr & 7, n = (rr >> 3) & 127, cq = rr >> 10;
        int k = (cq >> 2) * 32 + (cq & 3) * 8 + j;
        const float* W = (L == 0) ? W0 : (L == 1) ? W1 : (L == 2) ? W2 : W3;
        int Kin = (L == 0) ? 100 : 128;
        float v = (k < Kin) ? W[n*Kin + k] : 0.f;
        WB[r] = f2bf(v);
    } else if (i < 132096) {
        int t = i - 131072;
        bool val = t < N_FEATS;
        float lx = val ? locs[t*3+0] : 1e9f;
        float ly = val ? locs[t*3+1] : 1e9f;
        float lz = val ? locs[t*3+2] : 1e9f;
        LX[t] = lx; LY[t] = ly; LZ[t] = lz;
        SL[t] = lx*lx + ly*ly + lz*lz;          // 3e18 for pads -> never min
    }
}

// ---------------- main fused kernel ----------------
// 4 waves/block, 16 points/wave, no __syncthreads (act rows are wave-private).
// launch_bounds(256,8): 8 blocks/CU = 32 waves/CU (grid is exactly 8/CU).
// VGPR budget 64 -- round-0 body fit in 60; this body is register-leaner
// (unroll 1 + half-split chunk processing + half-split MLP accumulators).
__global__ __launch_bounds__(256, 8)
void afvsrn_mfma(const float* __restrict__ x,
                 const float* __restrict__ LX, const float* __restrict__ LY,
                 const float* __restrict__ LZ, const float* __restrict__ SL,
                 const unsigned short* __restrict__ fvB,
                 const unsigned short* __restrict__ WB,
                 const float* __restrict__ b0, const float* __restrict__ b1,
                 const float* __restrict__ b2, const float* __restrict__ b3,
                 const float* __restrict__ W4, const float* __restrict__ b4,
                 float* __restrict__ out)
{
    __shared__ unsigned short act[64 * 136];   // [64 pts][128 + 8 pad] bf16

    const int lane = threadIdx.x & 63;
    const int wv   = threadIdx.x >> 6;
    const int ptl  = lane & 15;                // A-frag row m / C-frag col n
    const int quad = lane >> 4;                // A/B-frag k-group, C-frag row-group
    const int ptbase = blockIdx.x * 64 + wv * 16;

    const float x0 = x[(ptbase + ptl)*3 + 0];
    const float x1 = x[(ptbase + ptl)*3 + 1];
    const float x2 = x[(ptbase + ptl)*3 + 2];
    const float A  = x0*x0 + x1*x1 + x2*x2;

    const f4* LX4 = (const f4*)LX;
    const f4* LY4 = (const f4*)LY;
    const f4* LZ4 = (const f4*)LZ;
    const f4* SL4 = (const f4*)SL;

    // ---------- pass 1: min shifted-d2 only (no transcendentals) ----------
    f4 mn = {1e30f, 1e30f, 1e30f, 1e30f};
    #pragma unroll 1
    for (int c = 0; c < NCHUNK; ++c) {
        int g = c*8 + quad*2;
        #pragma unroll
        for (int h = 0; h < 2; ++h) {
            f4 t = shifted_d2(LX4[g+h], LY4[g+h], LZ4[g+h], SL4[g+h], x0, x1, x2);
            mn = min4(mn, t);
        }
    }
    float md = fminf(fminf(mn[0], mn[1]), fminf(mn[2], mn[3]));
    md = fminf(md, __shfl_xor(md, 16));
    md = fminf(md, __shfl_xor(md, 32));
    // m = max inv_d = rsqrt(min d2). RN add is monotonic, so min over t + A
    // equals min over (t+A): pass-2 arg of rsq is bit-identical for the argmin.
    const float m   = __builtin_amdgcn_rsqf(fmaxf(md + A, 1e-12f));
    const float nmB = -m * L2E;

    // ---------- pass 2: p = exp2(fma(inv_d, log2e, -m*log2e)); GEMM feats = w @ fv ----------
    // ls comes free from an extra MFMA against an all-ones B tile: its C-frag
    // row (quad*4+r) is exactly the point whose linv each lane needs -> no shuffles.
    const short8 ONES = {0x3F80,0x3F80,0x3F80,0x3F80,0x3F80,0x3F80,0x3F80,0x3F80};
    floatx4 acc2[4] = {};
    floatx4 accL = {};
    #pragma unroll 1
    for (int c = 0; c < NCHUNK; ++c) {
        int g = c*8 + quad*2;
        // last chunk: features 992..1023, only quad 0 (992..999) is real.
        // nm = -inf makes exp2 return exactly 0 for the pad lanes.
        const float nm = ((c == NCHUNK-1) && (quad != 0)) ? -__builtin_inff() : nmB;
        union { short8 v; unsigned int u[4]; } af;
        #pragma unroll
        for (int h = 0; h < 2; ++h) {
            f4 t = shifted_d2(LX4[g+h], LY4[g+h], LZ4[g+h], SL4[g+h], x0, x1, x2);
            f4 p;
            #pragma unroll
            for (int e = 0; e < 4; ++e) {
                float iv = __builtin_amdgcn_rsqf(fmaxf(t[e] + A, 1e-12f));
                // clamp at 16: harmless normally (arg <= ~0), bounds p if rounding
                // between passes ever mismatches (2^16 is bf16-safe).
                p[e] = __builtin_amdgcn_exp2f(fminf(fmaf(iv, L2E, nm), 16.f));
            }
            af.u[2*h]   = packbf2(p[0], p[1]);
            af.u[2*h+1] = packbf2(p[2], p[3]);
        }
        const short8* bp = (const short8*)fvB + (c*4 + quad)*64;
        #pragma unroll
        for (int nt = 0; nt < 4; ++nt) {
            short8 b = bp[nt*16 + ptl];
            acc2[nt] = __builtin_amdgcn_mfma_f32_16x16x32_bf16(af.v, b, acc2[nt], 0, 0, 0);
        }
        accL = __builtin_amdgcn_mfma_f32_16x16x32_bf16(af.v, ONES, accL, 0, 0, 0);
    }
    float linv_r[4];
    #pragma unroll
    for (int r = 0; r < 4; ++r) linv_r[r] = __builtin_amdgcn_rcpf(accL[r]);

    // ---------- stage y = [PE(36) | feats(64) | zero pad to 128] ----------
    const int myrow = (wv*16 + ptl) * 136;
    *(short8*)&act[myrow + 96 + quad*8] = (short8)0;

    #pragma unroll
    for (int i = 0; i < 9; ++i) {
        int k = quad*9 + i;
        int d = k / 12, r12 = k % 12, l = r12 % 6;
        float xv = (d == 0) ? x0 : (d == 1) ? x1 : x2;
        float ang = xv * (PI_F * (float)(1 << l));
        float v = (r12 < 6) ? __sinf(ang) : __cosf(ang);
        act[myrow + k] = f2bf(v);
    }

    #pragma unroll
    for (int nt = 0; nt < 4; ++nt)
        #pragma unroll
        for (int r = 0; r < 4; ++r)
            act[(wv*16 + quad*4 + r)*136 + 36 + nt*16 + ptl] = f2bf(acc2[nt][r] * linv_r[r]);

    // ---------- MLP layers 0..3 via MFMA (nt split in halves: peak 16a+16acc regs) ----
    for (int Lyr = 0; Lyr < 4; ++Lyr) {
        const short8* WBp = (const short8*)(WB + Lyr*16384);
        const float* bL = (Lyr == 0) ? b0 : (Lyr == 1) ? b1 : (Lyr == 2) ? b2 : b3;

        short8 a[4];
        #pragma unroll
        for (int c = 0; c < 4; ++c)
            a[c] = *(const short8*)&act[myrow + c*32 + quad*8];

        #pragma unroll
        for (int half = 0; half < 2; ++half) {
            floatx4 acc[4] = {};
            #pragma unroll
            for (int nt = 0; nt < 4; ++nt) {
                #pragma unroll
                for (int c = 0; c < 4; ++c) {
                    short8 b = WBp[(c*4 + quad)*128 + (half*4 + nt)*16 + ptl];
                    acc[nt] = __builtin_amdgcn_mfma_f32_16x16x32_bf16(a[c], b, acc[nt], 0, 0, 0);
                }
            }
            #pragma unroll
            for (int nt = 0; nt < 4; ++nt) {
                float bias = bL[(half*4 + nt)*16 + ptl];
                #pragma unroll
                for (int r = 0; r < 4; ++r) {
                    float h = acc[nt][r] + bias;
                    float s = __sinf(h);
                    h = 0.5f*h + s*s;                       // SnakeAlt
                    act[(wv*16 + quad*4 + r)*136 + (half*4 + nt)*16 + ptl] = f2bf(h);
                }
            }
        }
    }

    // ---------- layer 4: 128 -> 1 ----------
    float o = 0.f;
    #pragma unroll
    for (int s = 0; s < 4; ++s) {
        short8 av = *(const short8*)&act[myrow + quad*32 + s*8];
        const floatx4* wp = (const floatx4*)W4 + (quad*32 + s*8)/4;
        floatx4 w0 = wp[0], w1 = wp[1];
        o = fmaf(bf2f((unsigned short)av[0]), w0[0], o);
        o = fmaf(bf2f((unsigned short)av[1]), w0[1], o);
        o = fmaf(bf2f((unsigned short)av[2]), w0[2], o);
        o = fmaf(bf2f((unsigned short)av[3]), w0[3], o);
        o = fmaf(bf2f((unsigned short)av[4]), w1[0], o);
        o = fmaf(bf2f((unsigned short)av[5]), w1[1], o);
        o = fmaf(bf2f((unsigned short)av[6]), w1[2], o);
        o = fmaf(bf2f((unsigned short)av[7]), w1[3], o);
    }
    o += __shfl_xor(o, 16);
    o += __shfl_xor(o, 32);
    if (quad == 0) out[ptbase + ptl] = o + b4[0];
}

extern "C" void kernel_launch(void* const* d_in, const int* in_sizes, int n_in,
                              void* d_out, int out_size, void* d_ws, size_t ws_size,
                              hipStream_t stream)
{
    const float* x  = (const float*)d_in[0];
    const float* lc = (const float*)d_in[1];
    const float* fv = (const float*)d_in[2];
    const float* W0 = (const float*)d_in[3];
    const float* b0 = (const float*)d_in[4];
    const float* W1 = (const float*)d_in[5];
    const float* b1 = (const float*)d_in[6];
    const float* W2 = (const float*)d_in[7];
    const float* b2 = (const float*)d_in[8];
    const float* W3 = (const float*)d_in[9];
    const float* b3 = (const float*)d_in[10];
    const float* W4 = (const float*)d_in[11];
    const float* b4 = (const float*)d_in[12];

    char* ws = (char*)d_ws;
    float*          LXp = (float*)(ws + 0);
    float*          LYp = (float*)(ws + 4096);
    float*          LZp = (float*)(ws + 8192);
    float*          SLp = (float*)(ws + 12288);
    unsigned short* fvB = (unsigned short*)(ws + 16384);            // 128 KB
    unsigned short* WB  = (unsigned short*)(ws + 16384 + 131072);   // 128 KB

    prep_all<<<dim3(516), dim3(256), 0, stream>>>(lc, fv, W0, W1, W2, W3,
                                                  LXp, LYp, LZp, SLp, fvB, WB);

    afvsrn_mfma<<<dim3(N_PTS/64), dim3(256), 0, stream>>>(
        x, LXp, LYp, LZp, SLp, fvB, WB, b0, b1, b2, b3, W4, b4, (float*)d_out);
}

// Round 3
// 234.688 us; speedup vs baseline: 1.1477x; 1.1280x over previous
//
#include <hip/hip_runtime.h>
#include <hip/hip_bf16.h>

#define N_PTS   131072
#define N_FEATS 1000
#define FDIM    64
#define HID     128
#define NCHUNK  32          // 32 K-chunks of 32 features (padded 1000 -> 1024)
#define PI_F    3.14159265358979f
#define L2E     1.44269504f

typedef short  short8  __attribute__((ext_vector_type(8)));   // bf16 A/B frag (4 VGPRs)
typedef float  floatx4 __attribute__((ext_vector_type(4)));   // C/D frag
typedef float  f4      __attribute__((ext_vector_type(4)));

// ---- bf16 helpers ----
__device__ __forceinline__ unsigned int packbf2(float a, float b) {
    float2 t; t.x = a; t.y = b;
    __hip_bfloat162 h = __float22bfloat162_rn(t);
    union { __hip_bfloat162 hh; unsigned int u; } cv; cv.hh = h;
    return cv.u;
}
__device__ __forceinline__ unsigned short f2bf(float f) {      // RNE, 1 v_cvt_pk
    return (unsigned short)packbf2(f, f);
}
__device__ __forceinline__ float bf2f(unsigned short h) {
    return __uint_as_float(((unsigned int)h) << 16);
}
__device__ __forceinline__ f4 min4(f4 a, f4 b) {
    f4 r;
    r[0] = fminf(a[0], b[0]); r[1] = fminf(a[1], b[1]);
    r[2] = fminf(a[2], b[2]); r[3] = fminf(a[3], b[3]);
    return r;
}
// shifted squared distance: t = |loc|^2 - 2 x.loc  (d2 = t + |x|^2)
// MUST be used identically in pass 1 and pass 2 so rounding matches exactly.
__device__ __forceinline__ f4 shifted_d2(f4 lx, f4 ly, f4 lz, f4 sl,
                                         float x0, float x1, float x2) {
    f4 d = lx*x0; d += ly*x1; d += lz*x2;       // mul + fma + fma
    return sl - 2.f*d;                          // fma(d, -2, sl)
}

// async global->LDS, 16B per lane (zero VGPR round-trip)
typedef const __attribute__((address_space(1))) unsigned int* gas1_t;
typedef __attribute__((address_space(3))) unsigned int*       las3_t;
__device__ __forceinline__ void async16(const void* g, void* l) {
    __builtin_amdgcn_global_load_lds((gas1_t)g, (las3_t)l, 16, 0, 0);
}

// ---------------- fused prep ----------------
// fvB: lane-linear staged layout, 8KB per 2-chunk group:
//   i = ((c*4 + nt)*64 + lane)*8 + j ; value = fv[f=c*32+(lane>>4)*8+j][n=nt*16+(lane&15)]
// WB: 16 stages (4 layers x 4 quarters) of 8KB:
//   r = ((((L*4+q)*2 + nt)*4 + c)*64 + lane)*8 + j
//   value = W_L[n=(q*2+nt)*16+(lane&15)][k=c*32+(lane>>4)*8+j], layer0 K padded 100->128
// LX/LY/LZ/SL [1024], pads at 1e9 (never the min distance)
__global__ void prep_all(const float* __restrict__ locs, const float* __restrict__ fv,
                         const float* __restrict__ W0, const float* __restrict__ W1,
                         const float* __restrict__ W2, const float* __restrict__ W3,
                         float* __restrict__ LX, float* __restrict__ LY, float* __restrict__ LZ,
                         float* __restrict__ SL,
                         unsigned short* __restrict__ fvB, unsigned short* __restrict__ WB)
{
    int i = blockIdx.x * 256 + threadIdx.x;
    if (i < 65536) {
        int j = i & 7, lane = (i >> 3) & 63, nt = (i >> 9) & 3, c = i >> 11;
        int f = c*32 + (lane >> 4)*8 + j;
        int n = nt*16 + (lane & 15);
        float v = (f < N_FEATS) ? fv[f*FDIM + n] : 0.f;
        fvB[i] = f2bf(v);
    } else if (i < 131072) {
        int r = i - 65536;
        int j = r & 7, lane = (r >> 3) & 63, c = (r >> 9) & 3;
        int nt = (r >> 11) & 1, q = (r >> 12) & 3, L = r >> 14;
        int n = (q*2 + nt)*16 + (lane & 15);
        int k = c*32 + (lane >> 4)*8 + j;
        const float* W = (L == 0) ? W0 : (L == 1) ? W1 : (L == 2) ? W2 : W3;
        int Kin = (L == 0) ? 100 : 128;
        float v = (k < Kin) ? W[n*Kin + k] : 0.f;
        WB[r] = f2bf(v);
    } else if (i < 132096) {
        int t = i - 131072;
        bool val = t < N_FEATS;
        float lx = val ? locs[t*3+0] : 1e9f;
        float ly = val ? locs[t*3+1] : 1e9f;
        float lz = val ? locs[t*3+2] : 1e9f;
        LX[t] = lx; LY[t] = ly; LZ[t] = lz;
        SL[t] = lx*lx + ly*ly + lz*lz;          // 3e18 for pads -> never min
    }
}

// ---------------- main fused kernel ----------------
// 4 waves/block, 16 points/wave. act rows are wave-private; __syncthreads only
// protects the shared staging buffer stg[2][8KB] (fvB groups, then WB stages).
// launch_bounds(256,4): VGPR budget 128 -> room for per-wave ILP (R2 lesson:
// (256,8) squeezed to 32 VGPRs and serialized on L2 latency).
__global__ __launch_bounds__(256, 4)
void afvsrn_mfma(const float* __restrict__ x,
                 const float* __restrict__ LX, const float* __restrict__ LY,
                 const float* __restrict__ LZ, const float* __restrict__ SL,
                 const unsigned short* __restrict__ fvB,
                 const unsigned short* __restrict__ WB,
                 const float* __restrict__ b0, const float* __restrict__ b1,
                 const float* __restrict__ b2, const float* __restrict__ b3,
                 const float* __restrict__ W4, const float* __restrict__ b4,
                 float* __restrict__ out)
{
    __shared__ unsigned short act[64 * 136];                  // [64 pts][128+8 pad] bf16
    __shared__ __align__(16) unsigned short stg[2][4096];     // 2 x 8KB staging dbuf

    const int lane = threadIdx.x & 63;
    const int wv   = threadIdx.x >> 6;
    const int ptl  = lane & 15;                // A-frag row m / C-frag col n
    const int quad = lane >> 4;                // A/B-frag k-group, C-frag row-group
    const int ptbase = blockIdx.x * 64 + wv * 16;

    const char* fvBb = (const char*)fvB;
    const char* WBb  = (const char*)WB;
    const int soff = wv*2048 + lane*16;        // this wave's slice of an 8KB stage

    // prefetch fvB group 0 (chunks 0,1) into stg[0]; latency hidden under pass 1
    async16(fvBb + soff,        (char*)&stg[0][0] + soff);
    async16(fvBb + soff + 1024, (char*)&stg[0][0] + soff + 1024);

    const float x0 = x[(ptbase + ptl)*3 + 0];
    const float x1 = x[(ptbase + ptl)*3 + 1];
    const float x2 = x[(ptbase + ptl)*3 + 2];
    const float A  = x0*x0 + x1*x1 + x2*x2;

    const f4* LX4 = (const f4*)LX;
    const f4* LY4 = (const f4*)LY;
    const f4* LZ4 = (const f4*)LZ;
    const f4* SL4 = (const f4*)SL;

    // ---------- pass 1: min shifted-d2 only (no transcendentals) ----------
    f4 mn = {1e30f, 1e30f, 1e30f, 1e30f};
    #pragma unroll 2
    for (int c = 0; c < NCHUNK; ++c) {
        int g = c*8 + quad*2;
        #pragma unroll
        for (int h = 0; h < 2; ++h) {
            f4 t = shifted_d2(LX4[g+h], LY4[g+h], LZ4[g+h], SL4[g+h], x0, x1, x2);
            mn = min4(mn, t);
        }
    }
    float md = fminf(fminf(mn[0], mn[1]), fminf(mn[2], mn[3]));
    md = fminf(md, __shfl_xor(md, 16));
    md = fminf(md, __shfl_xor(md, 32));
    // m = max inv_d = rsqrt(min d2). RN add is monotonic, so min over t + A
    // equals min over (t+A): pass-2 arg of rsq is bit-identical for the argmin.
    const float m   = __builtin_amdgcn_rsqf(fmaxf(md + A, 1e-12f));
    const float nmB = -m * L2E;

    __syncthreads();    // group-0 staging complete (drained by barrier)

    // ---------- pass 2: p = exp2(fma(inv_d, log2e, -m*log2e)); GEMM feats = w @ fv ----
    // ls comes free from an extra MFMA against an all-ones B tile: its C-frag
    // row (quad*4+r) is exactly the point whose linv each lane needs -> no shuffles.
    const short8 ONES = {0x3F80,0x3F80,0x3F80,0x3F80,0x3F80,0x3F80,0x3F80,0x3F80};
    floatx4 acc2[4] = {};
    floatx4 accL = {};
    #pragma unroll 1
    for (int grp = 0; grp < 16; ++grp) {
        if (grp < 15) {   // prefetch next 2-chunk group while computing this one
            const char* src = fvBb + (grp+1)*8192 + soff;
            char* dst = (char*)&stg[(grp+1)&1][0] + soff;
            async16(src, dst);
            async16(src + 1024, dst + 1024);
        }
        const short8* sb = (const short8*)&stg[grp&1][0];
        #pragma unroll
        for (int cc = 0; cc < 2; ++cc) {
            const int c = grp*2 + cc;
            const int g = c*8 + quad*2;
            // last chunk: features 992..1023, only quad 0 (992..999) is real.
            // nm = -inf makes exp2 return exactly 0 for the pad lanes.
            const float nm = ((c == NCHUNK-1) && (quad != 0)) ? -__builtin_inff() : nmB;
            union { short8 v; unsigned int u[4]; } af;
            #pragma unroll
            for (int h = 0; h < 2; ++h) {
                f4 t = shifted_d2(LX4[g+h], LY4[g+h], LZ4[g+h], SL4[g+h], x0, x1, x2);
                f4 p;
                #pragma unroll
                for (int e = 0; e < 4; ++e) {
                    float iv = __builtin_amdgcn_rsqf(fmaxf(t[e] + A, 1e-12f));
                    // clamp at 16: harmless normally (arg <= ~0), bounds p if rounding
                    // between passes ever mismatches (2^16 is bf16-safe).
                    p[e] = __builtin_amdgcn_exp2f(fminf(fmaf(iv, L2E, nm), 16.f));
                }
                af.u[2*h]   = packbf2(p[0], p[1]);
                af.u[2*h+1] = packbf2(p[2], p[3]);
            }
            #pragma unroll
            for (int nt = 0; nt < 4; ++nt) {
                short8 b = sb[cc*256 + nt*64 + lane];   // stride-16B lane-linear: conflict-free
                acc2[nt] = __builtin_amdgcn_mfma_f32_16x16x32_bf16(af.v, b, acc2[nt], 0, 0, 0);
            }
            accL = __builtin_amdgcn_mfma_f32_16x16x32_bf16(af.v, ONES, accL, 0, 0, 0);
        }
        __syncthreads();   // readers done + next group's copies drained
    }
    float linv_r[4];
    #pragma unroll
    for (int r = 0; r < 4; ++r) linv_r[r] = __builtin_amdgcn_rcpf(accL[r]);

    // prefetch WB stage 0 into stg[0]; latency hidden under the act epilogue
    async16(WBb + soff,        (char*)&stg[0][0] + soff);
    async16(WBb + soff + 1024, (char*)&stg[0][0] + soff + 1024);

    // ---------- stage y = [PE(36) | feats(64) | zero pad to 128] ----------
    const int myrow = (wv*16 + ptl) * 136;
    *(short8*)&act[myrow + 96 + quad*8] = (short8)0;

    #pragma unroll
    for (int i = 0; i < 9; ++i) {
        int k = quad*9 + i;
        int d = k / 12, r12 = k % 12, l = r12 % 6;
        float xv = (d == 0) ? x0 : (d == 1) ? x1 : x2;
        float ang = xv * (PI_F * (float)(1 << l));
        float v = (r12 < 6) ? __sinf(ang) : __cosf(ang);
        act[myrow + k] = f2bf(v);
    }

    #pragma unroll
    for (int nt = 0; nt < 4; ++nt)
        #pragma unroll
        for (int r = 0; r < 4; ++r)
            act[(wv*16 + quad*4 + r)*136 + 36 + nt*16 + ptl] = f2bf(acc2[nt][r] * linv_r[r]);

    __syncthreads();   // WB stage 0 staged

    // ---------- MLP layers 0..3 via MFMA, 16 pipelined 8KB weight stages ----------
    short8 a[4];
    #pragma unroll 1
    for (int t = 0; t < 16; ++t) {
        if (t < 15) {
            const char* src = WBb + (t+1)*8192 + soff;
            char* dst = (char*)&stg[(t+1)&1][0] + soff;
            async16(src, dst);
            async16(src + 1024, dst + 1024);
        }
        const int L = t >> 2, q = t & 3;
        if (q == 0) {      // new layer: capture input activations (wave-private rows)
            #pragma unroll
            for (int c = 0; c < 4; ++c)
                a[c] = *(const short8*)&act[myrow + c*32 + quad*8];
        }
        const float* bL = (L == 0) ? b0 : (L == 1) ? b1 : (L == 2) ? b2 : b3;
        const short8* bp = (const short8*)&stg[t&1][0];
        #pragma unroll
        for (int nt = 0; nt < 2; ++nt) {
            floatx4 acc = {};
            #pragma unroll
            for (int c = 0; c < 4; ++c)
                acc = __builtin_amdgcn_mfma_f32_16x16x32_bf16(a[c], bp[(nt*4 + c)*64 + lane],
                                                              acc, 0, 0, 0);
            const int col = (q*2 + nt)*16 + ptl;
            const float bias = bL[col];
            #pragma unroll
            for (int r = 0; r < 4; ++r) {
                float h = acc[r] + bias;
                float s = __sinf(h);
                h = 0.5f*h + s*s;                       // SnakeAlt
                act[(wv*16 + quad*4 + r)*136 + col] = f2bf(h);
            }
        }
        __syncthreads();
    }

    // ---------- layer 4: 128 -> 1 ----------
    float o = 0.f;
    #pragma unroll
    for (int s = 0; s < 4; ++s) {
        short8 av = *(const short8*)&act[myrow + quad*32 + s*8];
        const floatx4* wp = (const floatx4*)W4 + (quad*32 + s*8)/4;
        floatx4 w0 = wp[0], w1 = wp[1];
        o = fmaf(bf2f((unsigned short)av[0]), w0[0], o);
        o = fmaf(bf2f((unsigned short)av[1]), w0[1], o);
        o = fmaf(bf2f((unsigned short)av[2]), w0[2], o);
        o = fmaf(bf2f((unsigned short)av[3]), w0[3], o);
        o = fmaf(bf2f((unsigned short)av[4]), w1[0], o);
        o = fmaf(bf2f((unsigned short)av[5]), w1[1], o);
        o = fmaf(bf2f((unsigned short)av[6]), w1[2], o);
        o = fmaf(bf2f((unsigned short)av[7]), w1[3], o);
    }
    o += __shfl_xor(o, 16);
    o += __shfl_xor(o, 32);
    if (quad == 0) out[ptbase + ptl] = o + b4[0];
}

extern "C" void kernel_launch(void* const* d_in, const int* in_sizes, int n_in,
                              void* d_out, int out_size, void* d_ws, size_t ws_size,
                              hipStream_t stream)
{
    const float* x  = (const float*)d_in[0];
    const float* lc = (const float*)d_in[1];
    const float* fv = (const float*)d_in[2];
    const float* W0 = (const float*)d_in[3];
    const float* b0 = (const float*)d_in[4];
    const float* W1 = (const float*)d_in[5];
    const float* b1 = (const float*)d_in[6];
    const float* W2 = (const float*)d_in[7];
    const float* b2 = (const float*)d_in[8];
    const float* W3 = (const float*)d_in[9];
    const float* b3 = (const float*)d_in[10];
    const float* W4 = (const float*)d_in[11];
    const float* b4 = (const float*)d_in[12];

    char* ws = (char*)d_ws;
    float*          LXp = (float*)(ws + 0);
    float*          LYp = (float*)(ws + 4096);
    float*          LZp = (float*)(ws + 8192);
    float*          SLp = (float*)(ws + 12288);
    unsigned short* fvB = (unsigned short*)(ws + 16384);            // 128 KB
    unsigned short* WB  = (unsigned short*)(ws + 16384 + 131072);   // 128 KB

    prep_all<<<dim3(516), dim3(256), 0, stream>>>(lc, fv, W0, W1, W2, W3,
                                                  LXp, LYp, LZp, SLp, fvB, WB);

    afvsrn_mfma<<<dim3(N_PTS/64), dim3(256), 0, stream>>>(
        x, LXp, LYp, LZp, SLp, fvB, WB, b0, b1, b2, b3, W4, b4, (float*)d_out);
}

// Round 4
// 195.503 us; speedup vs baseline: 1.3778x; 1.2004x over previous
//
#include <hip/hip_runtime.h>
#include <hip/hip_bf16.h>

#define N_PTS   131072
#define N_FEATS 1000
#define FDIM    64
#define HID     128
#define NCHUNK  32          // 32 K-chunks of 32 features (padded 1000 -> 1024)
#define PI_F    3.14159265358979f
#define L2E     1.44269504f

typedef short  short8  __attribute__((ext_vector_type(8)));   // bf16 A/B frag (4 VGPRs)
typedef float  floatx4 __attribute__((ext_vector_type(4)));   // C/D frag
typedef float  f4      __attribute__((ext_vector_type(4)));

// ---- bf16 helpers ----
__device__ __forceinline__ unsigned int packbf2(float a, float b) {
    float2 t; t.x = a; t.y = b;
    __hip_bfloat162 h = __float22bfloat162_rn(t);
    union { __hip_bfloat162 hh; unsigned int u; } cv; cv.hh = h;
    return cv.u;
}
__device__ __forceinline__ unsigned short f2bf(float f) {      // RNE, 1 v_cvt_pk
    return (unsigned short)packbf2(f, f);
}
__device__ __forceinline__ float bf2f(unsigned short h) {
    return __uint_as_float(((unsigned int)h) << 16);
}
__device__ __forceinline__ f4 min4(f4 a, f4 b) {
    f4 r;
    r[0] = fminf(a[0], b[0]); r[1] = fminf(a[1], b[1]);
    r[2] = fminf(a[2], b[2]); r[3] = fminf(a[3], b[3]);
    return r;
}
// shifted squared distance: t = |loc|^2 - 2 x.loc  (d2 = t + |x|^2)
// MUST be used identically in pass 1 and pass 2 so rounding matches exactly.
__device__ __forceinline__ f4 shifted_d2(f4 lx, f4 ly, f4 lz, f4 sl,
                                         float x0, float x1, float x2) {
    f4 d = lx*x0; d += ly*x1; d += lz*x2;       // mul + fma + fma
    return sl - 2.f*d;                          // fma(d, -2, sl)
}

// async global->LDS, 16B per lane (zero VGPR round-trip)
typedef const __attribute__((address_space(1))) unsigned int* gas1_t;
typedef __attribute__((address_space(3))) unsigned int*       las3_t;
__device__ __forceinline__ void async16(const void* g, void* l) {
    __builtin_amdgcn_global_load_lds((gas1_t)g, (las3_t)l, 16, 0, 0);
}

// ---------------- fused prep ----------------
// fvB (direct-load fragment layout, round-0 style):
//   i = cq*512 + n*8 + j ; f = (cq>>2)*32 + (cq&3)*8 + j ; value = fv[f][n]
// WB: 16 stages (4 layers x 4 quarters) of 8KB, lane-linear for global_load_lds:
//   r = ((((L*4+q)*2 + nt)*4 + c)*64 + lane)*8 + j
//   value = W_L[n=(q*2+nt)*16+(lane&15)][k=c*32+(lane>>4)*8+j], layer0 K padded 100->128
// LX/LY/LZ/SL [1024], pads at 1e9 (never the min distance)
__global__ void prep_all(const float* __restrict__ locs, const float* __restrict__ fv,
                         const float* __restrict__ W0, const float* __restrict__ W1,
                         const float* __restrict__ W2, const float* __restrict__ W3,
                         float* __restrict__ LX, float* __restrict__ LY, float* __restrict__ LZ,
                         float* __restrict__ SL,
                         unsigned short* __restrict__ fvB, unsigned short* __restrict__ WB)
{
    int i = blockIdx.x * 256 + threadIdx.x;
    if (i < 65536) {
        int j = i & 7, n = (i >> 3) & 63, cq = i >> 9;
        int f = (cq >> 2) * 32 + (cq & 3) * 8 + j;
        float v = (f < N_FEATS) ? fv[f*FDIM + n] : 0.f;
        fvB[i] = f2bf(v);
    } else if (i < 131072) {
        int r = i - 65536;
        int j = r & 7, lane = (r >> 3) & 63, c = (r >> 9) & 3;
        int nt = (r >> 11) & 1, q = (r >> 12) & 3, L = r >> 14;
        int n = (q*2 + nt)*16 + (lane & 15);
        int k = c*32 + (lane >> 4)*8 + j;
        const float* W = (L == 0) ? W0 : (L == 1) ? W1 : (L == 2) ? W2 : W3;
        int Kin = (L == 0) ? 100 : 128;
        float v = (k < Kin) ? W[n*Kin + k] : 0.f;
        WB[r] = f2bf(v);
    } else if (i < 132096) {
        int t = i - 131072;
        bool val = t < N_FEATS;
        float lx = val ? locs[t*3+0] : 1e9f;
        float ly = val ? locs[t*3+1] : 1e9f;
        float lz = val ? locs[t*3+2] : 1e9f;
        LX[t] = lx; LY[t] = ly; LZ[t] = lz;
        SL[t] = lx*lx + ly*ly + lz*lz;          // 3e18 for pads -> never min
    }
}

// ---------------- main fused kernel ----------------
// 4 waves/block, 32 points/wave (TWO 16-pt A-tiles -> 2 independent dependency
// chains per chunk; loc loads, fvB B-frags, WB stages, W4 all amortized 2x).
// act rows are wave-private; __syncthreads only guards the MLP weight staging.
// launch_bounds(256,3): 3 blocks/CU (LDS-capped anyway), VGPR budget 168 so the
// doubled accumulator state fits without spill (R1 lesson) and keeps ILP (R2 lesson).
__global__ __launch_bounds__(256, 3)
void afvsrn_mfma(const float* __restrict__ x,
                 const float* __restrict__ LX, const float* __restrict__ LY,
                 const float* __restrict__ LZ, const float* __restrict__ SL,
                 const unsigned short* __restrict__ fvB,
                 const unsigned short* __restrict__ WB,
                 const float* __restrict__ b0, const float* __restrict__ b1,
                 const float* __restrict__ b2, const float* __restrict__ b3,
                 const float* __restrict__ W4, const float* __restrict__ b4,
                 float* __restrict__ out)
{
    __shared__ unsigned short act[128 * 136];                 // [128 pts][128+8 pad] bf16
    __shared__ __align__(16) unsigned short stg[2][4096];     // 2 x 8KB weight staging

    const int lane = threadIdx.x & 63;
    const int wv   = threadIdx.x >> 6;
    const int ptl  = lane & 15;                // A-frag row m / C-frag col n
    const int quad = lane >> 4;                // A/B-frag k-group, C-frag row-group
    const int ptbase = blockIdx.x * 128 + wv * 32;

    const float xA0 = x[(ptbase + ptl)*3 + 0];
    const float xA1 = x[(ptbase + ptl)*3 + 1];
    const float xA2 = x[(ptbase + ptl)*3 + 2];
    const float xB0 = x[(ptbase + 16 + ptl)*3 + 0];
    const float xB1 = x[(ptbase + 16 + ptl)*3 + 1];
    const float xB2 = x[(ptbase + 16 + ptl)*3 + 2];
    const float AA  = xA0*xA0 + xA1*xA1 + xA2*xA2;
    const float AB  = xB0*xB0 + xB1*xB1 + xB2*xB2;

    const f4* LX4 = (const f4*)LX;
    const f4* LY4 = (const f4*)LY;
    const f4* LZ4 = (const f4*)LZ;
    const f4* SL4 = (const f4*)SL;

    // ---------- pass 1: min shifted-d2 for both tiles (no transcendentals) ----------
    f4 mnA = {1e30f, 1e30f, 1e30f, 1e30f};
    f4 mnB = {1e30f, 1e30f, 1e30f, 1e30f};
    #pragma unroll 2
    for (int c = 0; c < NCHUNK; ++c) {
        int g = c*8 + quad*2;
        #pragma unroll
        for (int h = 0; h < 2; ++h) {
            f4 lx = LX4[g+h], ly = LY4[g+h], lz = LZ4[g+h], sl = SL4[g+h];
            mnA = min4(mnA, shifted_d2(lx, ly, lz, sl, xA0, xA1, xA2));
            mnB = min4(mnB, shifted_d2(lx, ly, lz, sl, xB0, xB1, xB2));
        }
    }
    float mdA = fminf(fminf(mnA[0], mnA[1]), fminf(mnA[2], mnA[3]));
    float mdB = fminf(fminf(mnB[0], mnB[1]), fminf(mnB[2], mnB[3]));
    mdA = fminf(mdA, __shfl_xor(mdA, 16));
    mdA = fminf(mdA, __shfl_xor(mdA, 32));
    mdB = fminf(mdB, __shfl_xor(mdB, 16));
    mdB = fminf(mdB, __shfl_xor(mdB, 32));
    // m = max inv_d = rsqrt(min d2). RN add is monotonic, so min over t + A
    // equals min over (t+A): pass-2 arg of rsq is bit-identical for the argmin.
    const float nmA = -__builtin_amdgcn_rsqf(fmaxf(mdA + AA, 1e-12f)) * L2E;
    const float nmB = -__builtin_amdgcn_rsqf(fmaxf(mdB + AB, 1e-12f)) * L2E;

    // ---------- pass 2: p = exp2(fma(inv_d, log2e, -m*log2e)); GEMM feats = w @ fv ----
    // B-frags loaded directly from L2-resident fvB (R3 showed staging == direct);
    // each B-frag feeds BOTH tiles' MFMAs. ls comes free from an extra MFMA against
    // an all-ones B tile: its C-frag row (quad*4+r) is exactly the point whose linv
    // each lane needs -> no shuffles.
    const short8 ONES = {0x3F80,0x3F80,0x3F80,0x3F80,0x3F80,0x3F80,0x3F80,0x3F80};
    floatx4 acc2A[4] = {}, acc2B[4] = {};
    floatx4 accLA = {}, accLB = {};
    #pragma unroll 1
    for (int c = 0; c < NCHUNK; ++c) {
        // B loads first: independent of the transcendental chains, ~200cy to hide
        const short8* bp = (const short8*)fvB + (c*4 + quad)*64;
        short8 bf0 = bp[ptl];
        short8 bf1 = bp[16 + ptl];
        short8 bf2 = bp[32 + ptl];
        short8 bf3 = bp[48 + ptl];

        const int g = c*8 + quad*2;
        // last chunk: features 992..1023, only quad 0 (992..999) is real.
        // nm = -inf makes exp2 return exactly 0 for the pad lanes.
        const bool pad = (c == NCHUNK-1) && (quad != 0);
        const float nmAe = pad ? -__builtin_inff() : nmA;
        const float nmBe = pad ? -__builtin_inff() : nmB;

        union { short8 v; unsigned int u[4]; } afA, afB;
        #pragma unroll
        for (int h = 0; h < 2; ++h) {
            f4 lx = LX4[g+h], ly = LY4[g+h], lz = LZ4[g+h], sl = SL4[g+h];
            f4 tA = shifted_d2(lx, ly, lz, sl, xA0, xA1, xA2);
            f4 tB = shifted_d2(lx, ly, lz, sl, xB0, xB1, xB2);
            f4 pA, pB;
            #pragma unroll
            for (int e = 0; e < 4; ++e) {
                float ivA = __builtin_amdgcn_rsqf(fmaxf(tA[e] + AA, 1e-12f));
                float ivB = __builtin_amdgcn_rsqf(fmaxf(tB[e] + AB, 1e-12f));
                // clamp at 16: harmless normally (arg <= ~0), bounds p if rounding
                // between passes ever mismatches (2^16 is bf16-safe).
                pA[e] = __builtin_amdgcn_exp2f(fminf(fmaf(ivA, L2E, nmAe), 16.f));
                pB[e] = __builtin_amdgcn_exp2f(fminf(fmaf(ivB, L2E, nmBe), 16.f));
            }
            afA.u[2*h]   = packbf2(pA[0], pA[1]);
            afA.u[2*h+1] = packbf2(pA[2], pA[3]);
            afB.u[2*h]   = packbf2(pB[0], pB[1]);
            afB.u[2*h+1] = packbf2(pB[2], pB[3]);
        }
        acc2A[0] = __builtin_amdgcn_mfma_f32_16x16x32_bf16(afA.v, bf0, acc2A[0], 0, 0, 0);
        acc2B[0] = __builtin_amdgcn_mfma_f32_16x16x32_bf16(afB.v, bf0, acc2B[0], 0, 0, 0);
        acc2A[1] = __builtin_amdgcn_mfma_f32_16x16x32_bf16(afA.v, bf1, acc2A[1], 0, 0, 0);
        acc2B[1] = __builtin_amdgcn_mfma_f32_16x16x32_bf16(afB.v, bf1, acc2B[1], 0, 0, 0);
        acc2A[2] = __builtin_amdgcn_mfma_f32_16x16x32_bf16(afA.v, bf2, acc2A[2], 0, 0, 0);
        acc2B[2] = __builtin_amdgcn_mfma_f32_16x16x32_bf16(afB.v, bf2, acc2B[2], 0, 0, 0);
        acc2A[3] = __builtin_amdgcn_mfma_f32_16x16x32_bf16(afA.v, bf3, acc2A[3], 0, 0, 0);
        acc2B[3] = __builtin_amdgcn_mfma_f32_16x16x32_bf16(afB.v, bf3, acc2B[3], 0, 0, 0);
        accLA = __builtin_amdgcn_mfma_f32_16x16x32_bf16(afA.v, ONES, accLA, 0, 0, 0);
        accLB = __builtin_amdgcn_mfma_f32_16x16x32_bf16(afB.v, ONES, accLB, 0, 0, 0);
    }

    // prefetch WB stage 0 into stg[0]; latency hidden under the act epilogue
    const char* WBb = (const char*)WB;
    const int soff = wv*2048 + lane*16;        // this wave's slice of an 8KB stage
    async16(WBb + soff,        (char*)&stg[0][0] + soff);
    async16(WBb + soff + 1024, (char*)&stg[0][0] + soff + 1024);

    float linvA[4], linvB[4];
    #pragma unroll
    for (int r = 0; r < 4; ++r) {
        linvA[r] = __builtin_amdgcn_rcpf(accLA[r]);
        linvB[r] = __builtin_amdgcn_rcpf(accLB[r]);
    }

    // ---------- stage y = [PE(36) | feats(64) | zero pad to 128] for both tiles ----
    const int myrowA = (wv*32 + ptl) * 136;
    const int myrowB = (wv*32 + 16 + ptl) * 136;
    *(short8*)&act[myrowA + 96 + quad*8] = (short8)0;
    *(short8*)&act[myrowB + 96 + quad*8] = (short8)0;

    #pragma unroll
    for (int i = 0; i < 9; ++i) {
        int k = quad*9 + i;
        int d = k / 12, r12 = k % 12, l = r12 % 6;
        float fr = PI_F * (float)(1 << l);
        float xvA = (d == 0) ? xA0 : (d == 1) ? xA1 : xA2;
        float xvB = (d == 0) ? xB0 : (d == 1) ? xB1 : xB2;
        float vA = (r12 < 6) ? __sinf(xvA * fr) : __cosf(xvA * fr);
        float vB = (r12 < 6) ? __sinf(xvB * fr) : __cosf(xvB * fr);
        act[myrowA + k] = f2bf(vA);
        act[myrowB + k] = f2bf(vB);
    }

    #pragma unroll
    for (int nt = 0; nt < 4; ++nt)
        #pragma unroll
        for (int r = 0; r < 4; ++r) {
            act[(wv*32 + quad*4 + r)*136 + 36 + nt*16 + ptl]      = f2bf(acc2A[nt][r] * linvA[r]);
            act[(wv*32 + 16 + quad*4 + r)*136 + 36 + nt*16 + ptl] = f2bf(acc2B[nt][r] * linvB[r]);
        }

    __syncthreads();   // WB stage 0 staged

    // ---------- MLP layers 0..3 via MFMA, 16 pipelined 8KB weight stages ----------
    short8 aA[4], aB[4];
    #pragma unroll 1
    for (int t = 0; t < 16; ++t) {
        if (t < 15) {
            const char* src = WBb + (t+1)*8192 + soff;
            char* dst = (char*)&stg[(t+1)&1][0] + soff;
            async16(src, dst);
            async16(src + 1024, dst + 1024);
        }
        const int L = t >> 2, q = t & 3;
        if (q == 0) {      // new layer: capture input activations (wave-private rows)
            #pragma unroll
            for (int c = 0; c < 4; ++c) {
                aA[c] = *(const short8*)&act[myrowA + c*32 + quad*8];
                aB[c] = *(const short8*)&act[myrowB + c*32 + quad*8];
            }
        }
        const float* bL = (L == 0) ? b0 : (L == 1) ? b1 : (L == 2) ? b2 : b3;
        const short8* bp = (const short8*)&stg[t&1][0];
        #pragma unroll
        for (int nt = 0; nt < 2; ++nt) {
            floatx4 accA = {}, accB = {};
            #pragma unroll
            for (int c = 0; c < 4; ++c) {
                short8 bw = bp[(nt*4 + c)*64 + lane];   // stride-16B lane-linear: conflict-free
                accA = __builtin_amdgcn_mfma_f32_16x16x32_bf16(aA[c], bw, accA, 0, 0, 0);
                accB = __builtin_amdgcn_mfma_f32_16x16x32_bf16(aB[c], bw, accB, 0, 0, 0);
            }
            const int col = (q*2 + nt)*16 + ptl;
            const float bias = bL[col];
            #pragma unroll
            for (int r = 0; r < 4; ++r) {
                float hA = accA[r] + bias;
                float hB = accB[r] + bias;
                float sA = __sinf(hA);
                float sB = __sinf(hB);
                hA = 0.5f*hA + sA*sA;                   // SnakeAlt
                hB = 0.5f*hB + sB*sB;
                act[(wv*32 + quad*4 + r)*136 + col]      = f2bf(hA);
                act[(wv*32 + 16 + quad*4 + r)*136 + col] = f2bf(hB);
            }
        }
        __syncthreads();
    }

    // ---------- layer 4: 128 -> 1 (W4 loads shared across both tiles) ----------
    float oA = 0.f, oB = 0.f;
    #pragma unroll
    for (int s = 0; s < 4; ++s) {
        short8 avA = *(const short8*)&act[myrowA + quad*32 + s*8];
        short8 avB = *(const short8*)&act[myrowB + quad*32 + s*8];
        const floatx4* wp = (const floatx4*)W4 + (quad*32 + s*8)/4;
        floatx4 w0 = wp[0], w1 = wp[1];
        oA = fmaf(bf2f((unsigned short)avA[0]), w0[0], oA);
        oB = fmaf(bf2f((unsigned short)avB[0]), w0[0], oB);
        oA = fmaf(bf2f((unsigned short)avA[1]), w0[1], oA);
        oB = fmaf(bf2f((unsigned short)avB[1]), w0[1], oB);
        oA = fmaf(bf2f((unsigned short)avA[2]), w0[2], oA);
        oB = fmaf(bf2f((unsigned short)avB[2]), w0[2], oB);
        oA = fmaf(bf2f((unsigned short)avA[3]), w0[3], oA);
        oB = fmaf(bf2f((unsigned short)avB[3]), w0[3], oB);
        oA = fmaf(bf2f((unsigned short)avA[4]), w1[0], oA);
        oB = fmaf(bf2f((unsigned short)avB[4]), w1[0], oB);
        oA = fmaf(bf2f((unsigned short)avA[5]), w1[1], oA);
        oB = fmaf(bf2f((unsigned short)avB[5]), w1[1], oB);
        oA = fmaf(bf2f((unsigned short)avA[6]), w1[2], oA);
        oB = fmaf(bf2f((unsigned short)avB[6]), w1[2], oB);
        oA = fmaf(bf2f((unsigned short)avA[7]), w1[3], oA);
        oB = fmaf(bf2f((unsigned short)avB[7]), w1[3], oB);
    }
    oA += __shfl_xor(oA, 16);
    oA += __shfl_xor(oA, 32);
    oB += __shfl_xor(oB, 16);
    oB += __shfl_xor(oB, 32);
    if (quad == 0) {
        float bb = b4[0];
        out[ptbase + ptl]      = oA + bb;
        out[ptbase + 16 + ptl] = oB + bb;
    }
}

extern "C" void kernel_launch(void* const* d_in, const int* in_sizes, int n_in,
                              void* d_out, int out_size, void* d_ws, size_t ws_size,
                              hipStream_t stream)
{
    const float* x  = (const float*)d_in[0];
    const float* lc = (const float*)d_in[1];
    const float* fv = (const float*)d_in[2];
    const float* W0 = (const float*)d_in[3];
    const float* b0 = (const float*)d_in[4];
    const float* W1 = (const float*)d_in[5];
    const float* b1 = (const float*)d_in[6];
    const float* W2 = (const float*)d_in[7];
    const float* b2 = (const float*)d_in[8];
    const float* W3 = (const float*)d_in[9];
    const float* b3 = (const float*)d_in[10];
    const float* W4 = (const float*)d_in[11];
    const float* b4 = (const float*)d_in[12];

    char* ws = (char*)d_ws;
    float*          LXp = (float*)(ws + 0);
    float*          LYp = (float*)(ws + 4096);
    float*          LZp = (float*)(ws + 8192);
    float*          SLp = (float*)(ws + 12288);
    unsigned short* fvB = (unsigned short*)(ws + 16384);            // 128 KB
    unsigned short* WB  = (unsigned short*)(ws + 16384 + 131072);   // 128 KB

    prep_all<<<dim3(516), dim3(256), 0, stream>>>(lc, fv, W0, W1, W2, W3,
                                                  LXp, LYp, LZp, SLp, fvB, WB);

    afvsrn_mfma<<<dim3(N_PTS/128), dim3(256), 0, stream>>>(
        x, LXp, LYp, LZp, SLp, fvB, WB, b0, b1, b2, b3, W4, b4, (float*)d_out);
}